// Round 1
// baseline (411.474 us; speedup 1.0000x reference)
//
#include <hip/hip_runtime.h>
#include <hip/hip_bf16.h>

#define NODES 32768
#define HD 128
#define NE 524288
#define NR 8

typedef unsigned int u32;
typedef unsigned short u16;
typedef __attribute__((ext_vector_type(8))) short bf16x8;
typedef __attribute__((ext_vector_type(4))) float f32x4;

// ---- ws byte offsets ----
#define XH_OFF   (0u)                      // bf16 hi, 8 MB
#define XL_OFF   (8u<<20)                  // bf16 lo, 8 MB
#define Y_OFF    (16u<<20)                 // bf16 y[8][NODES][128], 64 MB
#define Z_OFF    (80u<<20)                 // fp32 z[NODES][128], 16 MB
#define ADJ_OFF  (96u<<20)                 // u32 x NE (row ids)
#define RP_OFF   (98u<<20)                 // u32 x (NODES+1), block-local prefix
#define CUR_OFF  ((98u<<20)+(256u<<10))    // u32 x NODES
#define BSUM_OFF ((98u<<20)+(512u<<10))    // u32 x 129, block sums exclusive prefix
#define BP_OFF   ((98u<<20)+(640u<<10))    // packed weights bf16

#define BP_LAYER 294912                    // 9*2*16384
#define PP_ELEM  589824                    // pW packed at Bp+PP_ELEM (2 segs x 16384)

__device__ __forceinline__ float bflo(u32 u){ union{u32 i;float f;}c; c.i=u<<16; return c.f; }
__device__ __forceinline__ float bfhi(u32 u){ union{u32 i;float f;}c; c.i=u&0xffff0000u; return c.f; }
__device__ __forceinline__ u16 f2bf(float f){
  u32 u=__float_as_uint(f);
  u32 r=u + 0x7fffu + ((u>>16)&1u);
  return (u16)(r>>16);
}
__device__ __forceinline__ float bf2f(u16 h){ return __uint_as_float(((u32)h)<<16); }

__device__ __forceinline__ void gl_lds16(const void* g, void* l){
  __builtin_amdgcn_global_load_lds((const __attribute__((address_space(1))) u32*)g,
                                   (__attribute__((address_space(3))) u32*)l, 16, 0, 0);
}

// ---------------- weight prep: 2 layers x 9 tiles (8 rel + self) + pW, hi/lo segs ----
// MFMA-fragment-contiguous: k = ks*32 + q*8 + j -> (ks*128+n)*32 + q*8 + j
__global__ void prep_w(const float* __restrict__ rW, const float* __restrict__ sW,
                       const float* __restrict__ pWg, u16* __restrict__ Bp)
{
  int idx=blockIdx.x*256+threadIdx.x;           // 311296 total
  if(idx<294912){
    int l=idx/147456;
    int rem=idx%147456;
    int t=rem>>14;
    int kn=rem&16383;
    int k=kn>>7, n=kn&127;
    float w;
    if(t<8) w=rW[(((size_t)l*NR+t)*HD+n)*HD+k];
    else    w=sW[((size_t)l*HD+n)*HD+k];
    u16* base=Bp+(size_t)l*BP_LAYER+(size_t)t*32768;
    int ks=k>>5, q=(k>>3)&3, j=k&7;
    size_t off=((size_t)ks*128+n)*32+q*8+j;
    u16 hb=f2bf(w);
    u16 lb=f2bf(w-bf2f(hb));
    base[off]=hb;
    base[off+16384]=lb;
  } else {
    int kn=idx-294912;
    int k=kn>>7, n=kn&127;
    float w=pWg[(size_t)n*HD+k];
    u16* base=Bp+PP_ELEM;
    int ks=k>>5, q=(k>>3)&3, j=k&7;
    size_t off=((size_t)ks*128+n)*32+q*8+j;
    u16 hb=f2bf(w);
    u16 lb=f2bf(w-bf2f(hb));
    base[off]=hb;
    base[off+16384]=lb;
  }
}

// ---------------- embed_mfma: x = (cemb[cid]+kemb[kid]) @ pW^T + pb -> xh/xl ----------
// 128-row tile, LDS-staged hi/lo A, one barrier, same MFMA loop as gemm_y
__global__ __launch_bounds__(256,2) void embed_mfma(
    const int* __restrict__ cid, const int* __restrict__ kid,
    const float* __restrict__ cemb, const float* __restrict__ kemb,
    const u16* __restrict__ PP, const float* __restrict__ pb,
    u16* __restrict__ xh, u16* __restrict__ xl)
{
  __shared__ u16 Atile[2][128*128];   // [0]=hi [1]=lo, 64 KB, XOR-16 swizzle
  const int tid=threadIdx.x;
  const int wave=tid>>6, lane=tid&63;
  const int wm=wave>>1, wn=wave&1;
  const int q=lane>>4;
  const int d0=blockIdx.x*128;

  // ---- gather + add + split + LDS write: thread = (row=tid>>1, half=tid&1) ----
  { int r=tid>>1, half=tid&1;
    int ci=cid[d0+r], ki=kid[d0+r];
    const float* cp=cemb+(size_t)ci*HD+half*64;
    const float* kp=kemb+(size_t)ki*HD+half*64;
#pragma unroll
    for(int cc=0;cc<8;cc++){
      float4 a0=*(const float4*)(cp+cc*8);
      float4 a1=*(const float4*)(cp+cc*8+4);
      float4 b0=*(const float4*)(kp+cc*8);
      float4 b1=*(const float4*)(kp+cc*8+4);
      float v[8]={a0.x+b0.x,a0.y+b0.y,a0.z+b0.z,a0.w+b0.w,
                  a1.x+b1.x,a1.y+b1.y,a1.z+b1.z,a1.w+b1.w};
      u16 hb[8], lb[8];
#pragma unroll
      for(int j=0;j<8;j++){ hb[j]=f2bf(v[j]); lb[j]=f2bf(v[j]-bf2f(hb[j])); }
      int chunk=half*8+cc;
      int dst=r*128+(chunk^(r&15))*8;
      uint4 hv={(u32)hb[0]|((u32)hb[1]<<16),(u32)hb[2]|((u32)hb[3]<<16),
                (u32)hb[4]|((u32)hb[5]<<16),(u32)hb[6]|((u32)hb[7]<<16)};
      uint4 lv={(u32)lb[0]|((u32)lb[1]<<16),(u32)lb[2]|((u32)lb[3]<<16),
                (u32)lb[4]|((u32)lb[5]<<16),(u32)lb[6]|((u32)lb[7]<<16)};
      *(uint4*)&Atile[0][dst]=hv;
      *(uint4*)&Atile[1][dst]=lv;
    }
  }
  __syncthreads();

  f32x4 acc[4][4];
#pragma unroll
  for(int a=0;a<4;a++)
#pragma unroll
    for(int b=0;b<4;b++) acc[a][b]=(f32x4){0.f,0.f,0.f,0.f};

  // part 0: hi @ {Whi, Wlo}
#pragma unroll
  for(int ks=0;ks<4;ks++){
    bf16x8 ah[4];
#pragma unroll
    for(int tm=0;tm<4;tm++){
      int m=wm*64+tm*16+(lane&15);
      ah[tm]=*(const bf16x8*)&Atile[0][m*128+(((ks*4)+q)^(m&15))*8];
    }
#pragma unroll
    for(int s=0;s<2;s++){
      const u16* Bb=PP+s*16384;
#pragma unroll
      for(int tn=0;tn<4;tn++){
        int n=wn*64+tn*16+(lane&15);
        bf16x8 bfr=*(const bf16x8*)&Bb[((size_t)ks*128+n)*32+q*8];
#pragma unroll
        for(int tm=0;tm<4;tm++)
          acc[tm][tn]=__builtin_amdgcn_mfma_f32_16x16x32_bf16(ah[tm],bfr,acc[tm][tn],0,0,0);
      }
    }
  }
  // part 1: lo @ Whi
#pragma unroll
  for(int ks=0;ks<4;ks++){
    bf16x8 al[4];
#pragma unroll
    for(int tm=0;tm<4;tm++){
      int m=wm*64+tm*16+(lane&15);
      al[tm]=*(const bf16x8*)&Atile[1][m*128+(((ks*4)+q)^(m&15))*8];
    }
#pragma unroll
    for(int tn=0;tn<4;tn++){
      int n=wn*64+tn*16+(lane&15);
      bf16x8 bfr=*(const bf16x8*)&PP[((size_t)ks*128+n)*32+q*8];
#pragma unroll
      for(int tm=0;tm<4;tm++)
        acc[tm][tn]=__builtin_amdgcn_mfma_f32_16x16x32_bf16(al[tm],bfr,acc[tm][tn],0,0,0);
    }
  }

  // epilogue: +pb, split hi/lo; C/D layout col=lane&15, row=(lane>>4)*4+reg
#pragma unroll
  for(int tn=0;tn<4;tn++){
    int n=wn*64+tn*16+(lane&15);
    float b=pb[n];
#pragma unroll
    for(int tm=0;tm<4;tm++){
      int rbase=d0+wm*64+tm*16+q*4;
#pragma unroll
      for(int r=0;r<4;r++){
        float v=acc[tm][tn][r]+b;
        u16 hb=f2bf(v);
        u16 lb=f2bf(v-bf2f(hb));
        xh[(size_t)(rbase+r)*HD+n]=hb;
        xl[(size_t)(rbase+r)*HD+n]=lb;
      }
    }
  }
}

// ---------------- CSR build ----------------
__global__ void count_deg(const int* __restrict__ dst, u32* __restrict__ cnt){
  int e=blockIdx.x*256+threadIdx.x;
  atomicAdd(&cnt[dst[e]],1u);
}

__global__ void scan1(u32* __restrict__ cnt, u32* __restrict__ rp, u32* __restrict__ bsum){
  __shared__ u32 sh[256];
  int t=threadIdx.x; int base=blockIdx.x*256;
  u32 v=cnt[base+t]; sh[t]=v;
  cnt[base+t]=0u;                       // re-zero cur for scatter
  __syncthreads();
  for(int off=1;off<256;off<<=1){
    u32 tv=(t>=off)?sh[t-off]:0u; __syncthreads();
    sh[t]+=tv; __syncthreads();
  }
  rp[base+t]=sh[t]-v;
  if(t==255) bsum[blockIdx.x]=sh[255];
}

__global__ void scan2(u32* __restrict__ bsum, u32* __restrict__ rp){
  __shared__ u32 sh[128];
  int t=threadIdx.x;
  u32 v=bsum[t]; sh[t]=v; __syncthreads();
  for(int off=1;off<128;off<<=1){
    u32 tv=(t>=off)?sh[t-off]:0u; __syncthreads();
    sh[t]+=tv; __syncthreads();
  }
  bsum[t]=sh[t]-v;
  if(t==0){ rp[NODES]=NE; bsum[128]=0u; }
}

__global__ void scatter_edges(const int* __restrict__ src, const int* __restrict__ dst,
                              const int* __restrict__ et, const u32* __restrict__ rp,
                              const u32* __restrict__ bsum,
                              u32* __restrict__ cur, u32* __restrict__ adj){
  int e=blockIdx.x*256+threadIdx.x;
  int d=dst[e];
  u32 pos=atomicAdd(&cur[d],1u);
  adj[rp[d]+bsum[d>>8]+pos]=(u32)(et[e]*NODES+src[e]);   // precomputed y-row id
}

// ---------------- gemm_y: 128-row tile, t-GROUP per block, ONE barrier ----------------
// Stage x hi/lo once into LDS, then loop t over a group: y[t] = x @ W_t^T (t<8, bf16),
// z = x @ selfW^T (t==8, fp32). grid (NODES/128, 2): group0 = t 0..3, group1 = t 4..8.
// 2 blocks/CU (128 KB LDS) so one block's stage/epilogue hides under the other's MFMAs.
__global__ __launch_bounds__(256,2) void gemm_y(
    const u16* __restrict__ xhi, const u16* __restrict__ xlo,
    const u16* __restrict__ Bt, u16* __restrict__ y, float* __restrict__ z)
{
  __shared__ u16 Atile[2][128*128];   // [0]=hi [1]=lo; row=256B, XOR-16 swizzle
  const int tid=threadIdx.x;
  const int wave=tid>>6, lane=tid&63;
  const int wm=wave>>1, wn=wave&1;
  const int q=lane>>4;
  const int d0=blockIdx.x*128;

  const int st_c  = lane&15;
  const int st_rin= lane>>4;

#pragma unroll
  for(int i=0;i<8;i++){
    int rbase=wave*32+i*4;
    int r=rbase+st_rin;
    int g=st_c ^ (r&15);
    gl_lds16(xhi+(size_t)(d0+r)*HD+g*8, &Atile[0][rbase*128]);
  }
#pragma unroll
  for(int i=0;i<8;i++){
    int rbase=wave*32+i*4;
    int r=rbase+st_rin;
    int g=st_c ^ (r&15);
    gl_lds16(xlo+(size_t)(d0+r)*HD+g*8, &Atile[1][rbase*128]);
  }
  __syncthreads();

  const int t0   = blockIdx.y ? 4 : 0;
  const int tcnt = blockIdx.y ? 5 : 4;

#pragma unroll 1
  for(int ti=0; ti<tcnt; ++ti){
    const int t = t0 + ti;
    const u16* Btile=Bt+(size_t)t*32768;

    f32x4 acc[4][4];
#pragma unroll
    for(int a=0;a<4;a++)
#pragma unroll
      for(int b=0;b<4;b++) acc[a][b]=(f32x4){0.f,0.f,0.f,0.f};

    // part 0: xhi @ {Whi, Wlo}
#pragma unroll
    for(int ks=0;ks<4;ks++){
      bf16x8 ah[4];
#pragma unroll
      for(int tm=0;tm<4;tm++){
        int m=wm*64+tm*16+(lane&15);
        ah[tm]=*(const bf16x8*)&Atile[0][m*128+(((ks*4)+q)^(m&15))*8];
      }
#pragma unroll
      for(int s=0;s<2;s++){
        const u16* Bb=Btile+s*16384;
#pragma unroll
        for(int tn=0;tn<4;tn++){
          int n=wn*64+tn*16+(lane&15);
          bf16x8 bfr=*(const bf16x8*)&Bb[((size_t)ks*128+n)*32+q*8];
#pragma unroll
          for(int tm=0;tm<4;tm++)
            acc[tm][tn]=__builtin_amdgcn_mfma_f32_16x16x32_bf16(ah[tm],bfr,acc[tm][tn],0,0,0);
        }
      }
    }
    // part 1: xlo @ Whi
#pragma unroll
    for(int ks=0;ks<4;ks++){
      bf16x8 al[4];
#pragma unroll
      for(int tm=0;tm<4;tm++){
        int m=wm*64+tm*16+(lane&15);
        al[tm]=*(const bf16x8*)&Atile[1][m*128+(((ks*4)+q)^(m&15))*8];
      }
#pragma unroll
      for(int tn=0;tn<4;tn++){
        int n=wn*64+tn*16+(lane&15);
        bf16x8 bfr=*(const bf16x8*)&Btile[((size_t)ks*128+n)*32+q*8];
#pragma unroll
        for(int tm=0;tm<4;tm++)
          acc[tm][tn]=__builtin_amdgcn_mfma_f32_16x16x32_bf16(al[tm],bfr,acc[tm][tn],0,0,0);
      }
    }

    // epilogue: C/D layout col=lane&15, row=(lane>>4)*4+reg
    if(t<8){
      u16* yt=y+((size_t)t*NODES+d0)*HD;
#pragma unroll
      for(int tn=0;tn<4;tn++){
        int n=wn*64+tn*16+(lane&15);
#pragma unroll
        for(int tm=0;tm<4;tm++){
          int rbase=wm*64+tm*16+q*4;
#pragma unroll
          for(int r=0;r<4;r++)
            yt[(size_t)(rbase+r)*HD+n]=f2bf(acc[tm][tn][r]);
        }
      }
    } else {
      float* zt=z+(size_t)d0*HD;
#pragma unroll
      for(int tn=0;tn<4;tn++){
        int n=wn*64+tn*16+(lane&15);
#pragma unroll
        for(int tm=0;tm<4;tm++){
          int rbase=wm*64+tm*16+q*4;
#pragma unroll
          for(int r=0;r<4;r++)
            zt[(size_t)(rbase+r)*HD+n]=acc[tm][tn][r];
        }
      }
    }
  }
}

// ---------------- gather_combine: agg = (1/deg) * sum_e y[row_e]; out = relu(z+agg+b)
// wave per node; lane=(sub=lane>>5, c=lane&31); uint2 loads -> 2 rows per issue;
// adj read once per 64 edges (coalesced) and broadcast via shfl.
__global__ __launch_bounds__(256) void gather_combine(
    const uint2* __restrict__ yy, const float* __restrict__ z,
    const u32* __restrict__ adj, const u32* __restrict__ rp, const u32* __restrict__ bsum,
    const float* __restrict__ sb, const int* __restrict__ mask,
    u32* __restrict__ xh, u32* __restrict__ xl, float* __restrict__ outf, int last)
{
  const int wave=threadIdx.x>>6, lane=threadIdx.x&63;
  const int node=blockIdx.x*4+wave;
  const int sub=lane>>5, c=lane&31;
  const int beg=(int)(rp[node]+bsum[node>>8]);
  const int end=(int)(rp[node+1]+bsum[(node+1)>>8]);
  float a0=0.f,a1=0.f,a2=0.f,a3=0.f;

  for(int base=beg; base<end; base+=64){
    int nk=end-base; if(nk>64) nk=64;
    u32 adjv = (lane<nk) ? adj[base+lane] : 0u;
    int i=0;
    for(; i+16<=nk; i+=16){
      uint2 vv[8];
#pragma unroll
      for(int j=0;j<8;j++){
        u32 row=(u32)__shfl((int)adjv, i+j*2+sub);
        vv[j]=yy[(size_t)row*32+c];
      }
#pragma unroll
      for(int j=0;j<8;j++){
        a0+=bflo(vv[j].x); a1+=bfhi(vv[j].x);
        a2+=bflo(vv[j].y); a3+=bfhi(vv[j].y);
      }
    }
    for(; i+2<=nk; i+=2){
      u32 row=(u32)__shfl((int)adjv, i+sub);
      uint2 v=yy[(size_t)row*32+c];
      a0+=bflo(v.x); a1+=bfhi(v.x); a2+=bflo(v.y); a3+=bfhi(v.y);
    }
    if(i<nk){
      u32 row=(u32)__shfl((int)adjv, i);
      if(sub==0){
        uint2 v=yy[(size_t)row*32+c];
        a0+=bflo(v.x); a1+=bfhi(v.x); a2+=bflo(v.y); a3+=bfhi(v.y);
      }
    }
  }

  a0+=__shfl_xor(a0,32); a1+=__shfl_xor(a1,32);
  a2+=__shfl_xor(a2,32); a3+=__shfl_xor(a3,32);

  if(sub==0){
    float inv=1.f/fmaxf((float)(end-beg),1.f);
    float4 zz=*(const float4*)&z[(size_t)node*HD+c*4];
    float4 bb=*(const float4*)&sb[c*4];
    float v0=fmaxf(zz.x+a0*inv+bb.x,0.f);
    float v1=fmaxf(zz.y+a1*inv+bb.y,0.f);
    float v2=fmaxf(zz.z+a2*inv+bb.z,0.f);
    float v3=fmaxf(zz.w+a3*inv+bb.w,0.f);
    if(last){
      float mk=(float)mask[node];
      float4 o={v0*mk,v1*mk,v2*mk,v3*mk};
      *(float4*)&outf[(size_t)node*HD+c*4]=o;
    } else {
      u16 h0=f2bf(v0), h1=f2bf(v1), h2=f2bf(v2), h3=f2bf(v3);
      u16 l0=f2bf(v0-bf2f(h0)), l1=f2bf(v1-bf2f(h1));
      u16 l2=f2bf(v2-bf2f(h2)), l3=f2bf(v3-bf2f(h3));
      uint2 hv={(u32)h0|((u32)h1<<16),(u32)h2|((u32)h3<<16)};
      uint2 lv={(u32)l0|((u32)l1<<16),(u32)l2|((u32)l3<<16)};
      *(uint2*)&xh[(size_t)node*64+c*2]=hv;
      *(uint2*)&xl[(size_t)node*64+c*2]=lv;
    }
  }
}

extern "C" void kernel_launch(void* const* d_in, const int* in_sizes, int n_in,
                              void* d_out, int out_size, void* d_ws, size_t ws_size,
                              hipStream_t stream)
{
  (void)in_sizes; (void)n_in; (void)out_size; (void)ws_size;
  const int*   cid =(const int*)  d_in[0];
  const int*   kid =(const int*)  d_in[1];
  const int*   mask=(const int*)  d_in[2];
  const int*   ei  =(const int*)  d_in[3];
  const int*   et  =(const int*)  d_in[4];
  const float* cemb=(const float*)d_in[5];
  const float* kemb=(const float*)d_in[6];
  const float* pW  =(const float*)d_in[7];
  const float* pb  =(const float*)d_in[8];
  const float* sW  =(const float*)d_in[9];
  const float* sb  =(const float*)d_in[10];
  const float* rW  =(const float*)d_in[11];
  float* out=(float*)d_out;
  char*  ws =(char*)d_ws;

  u16* xh =(u16*)(ws+XH_OFF);
  u16* xl =(u16*)(ws+XL_OFF);
  u16* y  =(u16*)(ws+Y_OFF);
  float* z=(float*)(ws+Z_OFF);
  u32* adj =(u32*)(ws+ADJ_OFF);
  u32* rp  =(u32*)(ws+RP_OFF);
  u32* cur =(u32*)(ws+CUR_OFF);
  u32* bsum=(u32*)(ws+BSUM_OFF);
  u16* Bp  =(u16*)(ws+BP_OFF);
  const int* srcA=ei;
  const int* dstA=ei+NE;

  hipMemsetAsync(cur,0,NODES*sizeof(u32),stream);
  prep_w<<<1216,256,0,stream>>>(rW,sW,pW,Bp);
  embed_mfma<<<NODES/128,256,0,stream>>>(cid,kid,cemb,kemb,Bp+PP_ELEM,pb,xh,xl);
  count_deg<<<NE/256,256,0,stream>>>(dstA,cur);
  scan1<<<NODES/256,256,0,stream>>>(cur,rp,bsum);
  scan2<<<1,128,0,stream>>>(bsum,rp);
  scatter_edges<<<NE/256,256,0,stream>>>(srcA,dstA,et,rp,bsum,cur,adj);

  // layer 0
  gemm_y<<<dim3(NODES/128,2),256,0,stream>>>(xh,xl,Bp,y,z);
  gather_combine<<<NODES/4,256,0,stream>>>((const uint2*)y,z,adj,rp,bsum,sb,mask,(u32*)xh,(u32*)xl,out,0);
  // layer 1
  gemm_y<<<dim3(NODES/128,2),256,0,stream>>>(xh,xl,Bp+BP_LAYER,y,z);
  gather_combine<<<NODES/4,256,0,stream>>>((const uint2*)y,z,adj,rp,bsum,sb+HD,mask,(u32*)xh,(u32*)xl,out,1);
}

// Round 2
// 308.559 us; speedup vs baseline: 1.3335x; 1.3335x over previous
//
#include <hip/hip_runtime.h>
#include <hip/hip_bf16.h>

#define NODES 32768
#define HD 128
#define NE 524288
#define NR 8

typedef unsigned int u32;
typedef unsigned short u16;
typedef __attribute__((ext_vector_type(8))) short bf16x8;
typedef __attribute__((ext_vector_type(4))) float f32x4;

// ---- ws byte offsets ----
#define XH_OFF   (0u)                      // bf16 hi, 8 MB
#define XL_OFF   (8u<<20)                  // bf16 lo, 8 MB
#define Y_OFF    (16u<<20)                 // bf16 y[8][NODES][128], 64 MB
#define Z_OFF    (80u<<20)                 // fp32 z[NODES][128], 16 MB
#define ADJ_OFF  (96u<<20)                 // u32 x NE (row ids)
#define RP_OFF   (98u<<20)                 // u32 x (NODES+1), block-local prefix
#define CUR_OFF  ((98u<<20)+(256u<<10))    // u32 x NODES
#define BSUM_OFF ((98u<<20)+(512u<<10))    // u32 x 129, block sums exclusive prefix
#define BP_OFF   ((98u<<20)+(640u<<10))    // packed weights bf16

#define BP_LAYER 294912                    // 9*2*16384
#define PP_ELEM  589824                    // pW packed at Bp+PP_ELEM (2 segs x 16384)

__device__ __forceinline__ float bflo(u32 u){ union{u32 i;float f;}c; c.i=u<<16; return c.f; }
__device__ __forceinline__ float bfhi(u32 u){ union{u32 i;float f;}c; c.i=u&0xffff0000u; return c.f; }
__device__ __forceinline__ u16 f2bf(float f){
  u32 u=__float_as_uint(f);
  u32 r=u + 0x7fffu + ((u>>16)&1u);
  return (u16)(r>>16);
}
__device__ __forceinline__ float bf2f(u16 h){ return __uint_as_float(((u32)h)<<16); }

__device__ __forceinline__ void gl_lds16(const void* g, void* l){
  __builtin_amdgcn_global_load_lds((const __attribute__((address_space(1))) u32*)g,
                                   (__attribute__((address_space(3))) u32*)l, 16, 0, 0);
}

// ---------------- weight prep: 2 layers x 9 tiles (8 rel + self) + pW, hi/lo segs ----
// MFMA-fragment-contiguous: k = ks*32 + q*8 + j -> (ks*128+n)*32 + q*8 + j
__global__ void prep_w(const float* __restrict__ rW, const float* __restrict__ sW,
                       const float* __restrict__ pWg, u16* __restrict__ Bp)
{
  int idx=blockIdx.x*256+threadIdx.x;           // 311296 total
  if(idx<294912){
    int l=idx/147456;
    int rem=idx%147456;
    int t=rem>>14;
    int kn=rem&16383;
    int k=kn>>7, n=kn&127;
    float w;
    if(t<8) w=rW[(((size_t)l*NR+t)*HD+n)*HD+k];
    else    w=sW[((size_t)l*HD+n)*HD+k];
    u16* base=Bp+(size_t)l*BP_LAYER+(size_t)t*32768;
    int ks=k>>5, q=(k>>3)&3, j=k&7;
    size_t off=((size_t)ks*128+n)*32+q*8+j;
    u16 hb=f2bf(w);
    u16 lb=f2bf(w-bf2f(hb));
    base[off]=hb;
    base[off+16384]=lb;
  } else {
    int kn=idx-294912;
    int k=kn>>7, n=kn&127;
    float w=pWg[(size_t)n*HD+k];
    u16* base=Bp+PP_ELEM;
    int ks=k>>5, q=(k>>3)&3, j=k&7;
    size_t off=((size_t)ks*128+n)*32+q*8+j;
    u16 hb=f2bf(w);
    u16 lb=f2bf(w-bf2f(hb));
    base[off]=hb;
    base[off+16384]=lb;
  }
}

// ---------------- embed_mfma: x = (cemb[cid]+kemb[kid]) @ pW^T + pb -> xh/xl ----------
// 128-row tile, LDS-staged hi/lo A, one barrier, same MFMA loop structure as gemm_y
__global__ __launch_bounds__(256,2) void embed_mfma(
    const int* __restrict__ cid, const int* __restrict__ kid,
    const float* __restrict__ cemb, const float* __restrict__ kemb,
    const u16* __restrict__ PP, const float* __restrict__ pb,
    u16* __restrict__ xh, u16* __restrict__ xl)
{
  __shared__ u16 Atile[2][128*128];   // [0]=hi [1]=lo, 64 KB, XOR-16 swizzle
  const int tid=threadIdx.x;
  const int wave=tid>>6, lane=tid&63;
  const int wm=wave>>1, wn=wave&1;
  const int q=lane>>4;
  const int d0=blockIdx.x*128;

  // ---- gather + add + split + LDS write: thread = (row=tid>>1, half=tid&1) ----
  { int r=tid>>1, half=tid&1;
    int ci=cid[d0+r], ki=kid[d0+r];
    const float* cp=cemb+(size_t)ci*HD+half*64;
    const float* kp=kemb+(size_t)ki*HD+half*64;
#pragma unroll
    for(int cc=0;cc<8;cc++){
      float4 a0=*(const float4*)(cp+cc*8);
      float4 a1=*(const float4*)(cp+cc*8+4);
      float4 b0=*(const float4*)(kp+cc*8);
      float4 b1=*(const float4*)(kp+cc*8+4);
      float v[8]={a0.x+b0.x,a0.y+b0.y,a0.z+b0.z,a0.w+b0.w,
                  a1.x+b1.x,a1.y+b1.y,a1.z+b1.z,a1.w+b1.w};
      u16 hb[8], lb[8];
#pragma unroll
      for(int j=0;j<8;j++){ hb[j]=f2bf(v[j]); lb[j]=f2bf(v[j]-bf2f(hb[j])); }
      int chunk=half*8+cc;
      int dst=r*128+(chunk^(r&15))*8;
      uint4 hv={(u32)hb[0]|((u32)hb[1]<<16),(u32)hb[2]|((u32)hb[3]<<16),
                (u32)hb[4]|((u32)hb[5]<<16),(u32)hb[6]|((u32)hb[7]<<16)};
      uint4 lv={(u32)lb[0]|((u32)lb[1]<<16),(u32)lb[2]|((u32)lb[3]<<16),
                (u32)lb[4]|((u32)lb[5]<<16),(u32)lb[6]|((u32)lb[7]<<16)};
      *(uint4*)&Atile[0][dst]=hv;
      *(uint4*)&Atile[1][dst]=lv;
    }
  }
  __syncthreads();

  f32x4 acc[4][4];
#pragma unroll
  for(int a=0;a<4;a++)
#pragma unroll
    for(int b=0;b<4;b++) acc[a][b]=(f32x4){0.f,0.f,0.f,0.f};

  // part 0: hi @ {Whi, Wlo}
#pragma unroll
  for(int ks=0;ks<4;ks++){
    bf16x8 ah[4];
#pragma unroll
    for(int tm=0;tm<4;tm++){
      int m=wm*64+tm*16+(lane&15);
      ah[tm]=*(const bf16x8*)&Atile[0][m*128+(((ks*4)+q)^(m&15))*8];
    }
#pragma unroll
    for(int s=0;s<2;s++){
      const u16* Bb=PP+s*16384;
#pragma unroll
      for(int tn=0;tn<4;tn++){
        int n=wn*64+tn*16+(lane&15);
        bf16x8 bfr=*(const bf16x8*)&Bb[((size_t)ks*128+n)*32+q*8];
#pragma unroll
        for(int tm=0;tm<4;tm++)
          acc[tm][tn]=__builtin_amdgcn_mfma_f32_16x16x32_bf16(ah[tm],bfr,acc[tm][tn],0,0,0);
      }
    }
  }
  // part 1: lo @ Whi
#pragma unroll
  for(int ks=0;ks<4;ks++){
    bf16x8 al[4];
#pragma unroll
    for(int tm=0;tm<4;tm++){
      int m=wm*64+tm*16+(lane&15);
      al[tm]=*(const bf16x8*)&Atile[1][m*128+(((ks*4)+q)^(m&15))*8];
    }
#pragma unroll
    for(int tn=0;tn<4;tn++){
      int n=wn*64+tn*16+(lane&15);
      bf16x8 bfr=*(const bf16x8*)&PP[((size_t)ks*128+n)*32+q*8];
#pragma unroll
      for(int tm=0;tm<4;tm++)
        acc[tm][tn]=__builtin_amdgcn_mfma_f32_16x16x32_bf16(al[tm],bfr,acc[tm][tn],0,0,0);
    }
  }

  // epilogue: +pb, split hi/lo; C/D layout col=lane&15, row=(lane>>4)*4+reg
#pragma unroll
  for(int tn=0;tn<4;tn++){
    int n=wn*64+tn*16+(lane&15);
    float b=pb[n];
#pragma unroll
    for(int tm=0;tm<4;tm++){
      int rbase=d0+wm*64+tm*16+q*4;
#pragma unroll
      for(int r=0;r<4;r++){
        float v=acc[tm][tn][r]+b;
        u16 hb=f2bf(v);
        u16 lb=f2bf(v-bf2f(hb));
        xh[(size_t)(rbase+r)*HD+n]=hb;
        xl[(size_t)(rbase+r)*HD+n]=lb;
      }
    }
  }
}

// ---------------- CSR build ----------------
__global__ void count_deg(const int* __restrict__ dst, u32* __restrict__ cnt){
  int e=blockIdx.x*256+threadIdx.x;
  atomicAdd(&cnt[dst[e]],1u);
}

__global__ void scan1(u32* __restrict__ cnt, u32* __restrict__ rp, u32* __restrict__ bsum){
  __shared__ u32 sh[256];
  int t=threadIdx.x; int base=blockIdx.x*256;
  u32 v=cnt[base+t]; sh[t]=v;
  cnt[base+t]=0u;                       // re-zero cur for scatter
  __syncthreads();
  for(int off=1;off<256;off<<=1){
    u32 tv=(t>=off)?sh[t-off]:0u; __syncthreads();
    sh[t]+=tv; __syncthreads();
  }
  rp[base+t]=sh[t]-v;
  if(t==255) bsum[blockIdx.x]=sh[255];
}

__global__ void scan2(u32* __restrict__ bsum, u32* __restrict__ rp){
  __shared__ u32 sh[128];
  int t=threadIdx.x;
  u32 v=bsum[t]; sh[t]=v; __syncthreads();
  for(int off=1;off<128;off<<=1){
    u32 tv=(t>=off)?sh[t-off]:0u; __syncthreads();
    sh[t]+=tv; __syncthreads();
  }
  bsum[t]=sh[t]-v;
  if(t==0){ rp[NODES]=NE; bsum[128]=0u; }
}

__global__ void scatter_edges(const int* __restrict__ src, const int* __restrict__ dst,
                              const int* __restrict__ et, const u32* __restrict__ rp,
                              const u32* __restrict__ bsum,
                              u32* __restrict__ cur, u32* __restrict__ adj){
  int e=blockIdx.x*256+threadIdx.x;
  int d=dst[e];
  u32 pos=atomicAdd(&cur[d],1u);
  adj[rp[d]+bsum[d>>8]+pos]=(u32)(et[e]*NODES+src[e]);   // precomputed y-row id
}

// ---------------- gemm_y: 64-row tile, ONE t per block, ONE barrier ----------------
// y[t] = x @ W_t^T (t<8, bf16 out), z = x @ selfW^T (t==8, fp32 out)
// grid (NODES/64, 9) = 4608 blocks; 4 waves = 4 column-strips of a 64x128 tile.
// LDS 32 KB -> up to 5 blocks/CU resident: inter-block overlap hides stage drain,
// B-load latency, and epilogue scatter (R1 lesson: TLP across blocks > staging dedup).
__global__ __launch_bounds__(256,4) void gemm_y(
    const u16* __restrict__ xhi, const u16* __restrict__ xlo,
    const u16* __restrict__ Bt, u16* __restrict__ y, float* __restrict__ z)
{
  __shared__ u16 Atile[2][64*128];    // [0]=hi [1]=lo; row=256B, XOR-16 swizzle; 32 KB
  const int tid=threadIdx.x;
  const int wave=tid>>6, lane=tid&63;
  const int q=lane>>4;
  const int d0=blockIdx.x*64;
  const int t=blockIdx.y;
  const u16* Btile=Bt+(size_t)t*32768;

  const int st_c  = lane&15;
  const int st_rin= lane>>4;

#pragma unroll
  for(int i=0;i<4;i++){
    int rbase=wave*16+i*4;
    int r=rbase+st_rin;
    int g=st_c ^ (r&15);
    gl_lds16(xhi+(size_t)(d0+r)*HD+g*8, &Atile[0][rbase*128]);
  }
#pragma unroll
  for(int i=0;i<4;i++){
    int rbase=wave*16+i*4;
    int r=rbase+st_rin;
    int g=st_c ^ (r&15);
    gl_lds16(xlo+(size_t)(d0+r)*HD+g*8, &Atile[1][rbase*128]);
  }
  __syncthreads();

  f32x4 acc[4][2];
#pragma unroll
  for(int a=0;a<4;a++)
#pragma unroll
    for(int b=0;b<2;b++) acc[a][b]=(f32x4){0.f,0.f,0.f,0.f};

  // part 0: xhi @ {Whi, Wlo}
#pragma unroll
  for(int ks=0;ks<4;ks++){
    bf16x8 ah[4];
#pragma unroll
    for(int tm=0;tm<4;tm++){
      int m=tm*16+(lane&15);
      ah[tm]=*(const bf16x8*)&Atile[0][m*128+(((ks*4)+q)^(m&15))*8];
    }
#pragma unroll
    for(int s=0;s<2;s++){
      const u16* Bb=Btile+s*16384;
#pragma unroll
      for(int tn=0;tn<2;tn++){
        int n=wave*32+tn*16+(lane&15);
        bf16x8 bfr=*(const bf16x8*)&Bb[((size_t)ks*128+n)*32+q*8];
#pragma unroll
        for(int tm=0;tm<4;tm++)
          acc[tm][tn]=__builtin_amdgcn_mfma_f32_16x16x32_bf16(ah[tm],bfr,acc[tm][tn],0,0,0);
      }
    }
  }
  // part 1: xlo @ Whi
#pragma unroll
  for(int ks=0;ks<4;ks++){
    bf16x8 al[4];
#pragma unroll
    for(int tm=0;tm<4;tm++){
      int m=tm*16+(lane&15);
      al[tm]=*(const bf16x8*)&Atile[1][m*128+(((ks*4)+q)^(m&15))*8];
    }
#pragma unroll
    for(int tn=0;tn<2;tn++){
      int n=wave*32+tn*16+(lane&15);
      bf16x8 bfr=*(const bf16x8*)&Btile[((size_t)ks*128+n)*32+q*8];
#pragma unroll
      for(int tm=0;tm<4;tm++)
        acc[tm][tn]=__builtin_amdgcn_mfma_f32_16x16x32_bf16(al[tm],bfr,acc[tm][tn],0,0,0);
    }
  }

  // epilogue: C/D layout col=lane&15, row=(lane>>4)*4+reg
  if(t<8){
    u16* yt=y+((size_t)t*NODES+d0)*HD;
#pragma unroll
    for(int tn=0;tn<2;tn++){
      int n=wave*32+tn*16+(lane&15);
#pragma unroll
      for(int tm=0;tm<4;tm++){
        int rbase=tm*16+q*4;
#pragma unroll
        for(int r=0;r<4;r++)
          yt[(size_t)(rbase+r)*HD+n]=f2bf(acc[tm][tn][r]);
      }
    }
  } else {
    float* zt=z+(size_t)d0*HD;
#pragma unroll
    for(int tn=0;tn<2;tn++){
      int n=wave*32+tn*16+(lane&15);
#pragma unroll
      for(int tm=0;tm<4;tm++){
        int rbase=tm*16+q*4;
#pragma unroll
        for(int r=0;r<4;r++)
          zt[(size_t)(rbase+r)*HD+n]=acc[tm][tn][r];
      }
    }
  }
}

// ---------------- gather_combine: agg = (1/deg) * sum_e y[row_e]; out = relu(z+agg+b)
// wave per node; lane=(sub=lane>>5, c=lane&31); uint2 loads -> 2 rows per issue;
// adj read once per 64 edges (coalesced) and broadcast via shfl.
__global__ __launch_bounds__(256) void gather_combine(
    const uint2* __restrict__ yy, const float* __restrict__ z,
    const u32* __restrict__ adj, const u32* __restrict__ rp, const u32* __restrict__ bsum,
    const float* __restrict__ sb, const int* __restrict__ mask,
    u32* __restrict__ xh, u32* __restrict__ xl, float* __restrict__ outf, int last)
{
  const int wave=threadIdx.x>>6, lane=threadIdx.x&63;
  const int node=blockIdx.x*4+wave;
  const int sub=lane>>5, c=lane&31;
  const int beg=(int)(rp[node]+bsum[node>>8]);
  const int end=(int)(rp[node+1]+bsum[(node+1)>>8]);
  float a0=0.f,a1=0.f,a2=0.f,a3=0.f;

  for(int base=beg; base<end; base+=64){
    int nk=end-base; if(nk>64) nk=64;
    u32 adjv = (lane<nk) ? adj[base+lane] : 0u;
    int i=0;
    for(; i+16<=nk; i+=16){
      uint2 vv[8];
#pragma unroll
      for(int j=0;j<8;j++){
        u32 row=(u32)__shfl((int)adjv, i+j*2+sub);
        vv[j]=yy[(size_t)row*32+c];
      }
#pragma unroll
      for(int j=0;j<8;j++){
        a0+=bflo(vv[j].x); a1+=bfhi(vv[j].x);
        a2+=bflo(vv[j].y); a3+=bfhi(vv[j].y);
      }
    }
    for(; i+2<=nk; i+=2){
      u32 row=(u32)__shfl((int)adjv, i+sub);
      uint2 v=yy[(size_t)row*32+c];
      a0+=bflo(v.x); a1+=bfhi(v.x); a2+=bflo(v.y); a3+=bfhi(v.y);
    }
    if(i<nk){
      u32 row=(u32)__shfl((int)adjv, i);
      if(sub==0){
        uint2 v=yy[(size_t)row*32+c];
        a0+=bflo(v.x); a1+=bfhi(v.x); a2+=bflo(v.y); a3+=bfhi(v.y);
      }
    }
  }

  a0+=__shfl_xor(a0,32); a1+=__shfl_xor(a1,32);
  a2+=__shfl_xor(a2,32); a3+=__shfl_xor(a3,32);

  if(sub==0){
    float inv=1.f/fmaxf((float)(end-beg),1.f);
    float4 zz=*(const float4*)&z[(size_t)node*HD+c*4];
    float4 bb=*(const float4*)&sb[c*4];
    float v0=fmaxf(zz.x+a0*inv+bb.x,0.f);
    float v1=fmaxf(zz.y+a1*inv+bb.y,0.f);
    float v2=fmaxf(zz.z+a2*inv+bb.z,0.f);
    float v3=fmaxf(zz.w+a3*inv+bb.w,0.f);
    if(last){
      float mk=(float)mask[node];
      float4 o={v0*mk,v1*mk,v2*mk,v3*mk};
      *(float4*)&outf[(size_t)node*HD+c*4]=o;
    } else {
      u16 h0=f2bf(v0), h1=f2bf(v1), h2=f2bf(v2), h3=f2bf(v3);
      u16 l0=f2bf(v0-bf2f(h0)), l1=f2bf(v1-bf2f(h1));
      u16 l2=f2bf(v2-bf2f(h2)), l3=f2bf(v3-bf2f(h3));
      uint2 hv={(u32)h0|((u32)h1<<16),(u32)h2|((u32)h3<<16)};
      uint2 lv={(u32)l0|((u32)l1<<16),(u32)l2|((u32)l3<<16)};
      *(uint2*)&xh[(size_t)node*64+c*2]=hv;
      *(uint2*)&xl[(size_t)node*64+c*2]=lv;
    }
  }
}

extern "C" void kernel_launch(void* const* d_in, const int* in_sizes, int n_in,
                              void* d_out, int out_size, void* d_ws, size_t ws_size,
                              hipStream_t stream)
{
  (void)in_sizes; (void)n_in; (void)out_size; (void)ws_size;
  const int*   cid =(const int*)  d_in[0];
  const int*   kid =(const int*)  d_in[1];
  const int*   mask=(const int*)  d_in[2];
  const int*   ei  =(const int*)  d_in[3];
  const int*   et  =(const int*)  d_in[4];
  const float* cemb=(const float*)d_in[5];
  const float* kemb=(const float*)d_in[6];
  const float* pW  =(const float*)d_in[7];
  const float* pb  =(const float*)d_in[8];
  const float* sW  =(const float*)d_in[9];
  const float* sb  =(const float*)d_in[10];
  const float* rW  =(const float*)d_in[11];
  float* out=(float*)d_out;
  char*  ws =(char*)d_ws;

  u16* xh =(u16*)(ws+XH_OFF);
  u16* xl =(u16*)(ws+XL_OFF);
  u16* y  =(u16*)(ws+Y_OFF);
  float* z=(float*)(ws+Z_OFF);
  u32* adj =(u32*)(ws+ADJ_OFF);
  u32* rp  =(u32*)(ws+RP_OFF);
  u32* cur =(u32*)(ws+CUR_OFF);
  u32* bsum=(u32*)(ws+BSUM_OFF);
  u16* Bp  =(u16*)(ws+BP_OFF);
  const int* srcA=ei;
  const int* dstA=ei+NE;

  hipMemsetAsync(cur,0,NODES*sizeof(u32),stream);
  prep_w<<<1216,256,0,stream>>>(rW,sW,pW,Bp);
  embed_mfma<<<NODES/128,256,0,stream>>>(cid,kid,cemb,kemb,Bp+PP_ELEM,pb,xh,xl);
  count_deg<<<NE/256,256,0,stream>>>(dstA,cur);
  scan1<<<NODES/256,256,0,stream>>>(cur,rp,bsum);
  scan2<<<1,128,0,stream>>>(bsum,rp);
  scatter_edges<<<NE/256,256,0,stream>>>(srcA,dstA,et,rp,bsum,cur,adj);

  // layer 0
  gemm_y<<<dim3(NODES/64,9),256,0,stream>>>(xh,xl,Bp,y,z);
  gather_combine<<<NODES/4,256,0,stream>>>((const uint2*)y,z,adj,rp,bsum,sb,mask,(u32*)xh,(u32*)xl,out,0);
  // layer 1
  gemm_y<<<dim3(NODES/64,9),256,0,stream>>>(xh,xl,Bp+BP_LAYER,y,z);
  gather_combine<<<NODES/4,256,0,stream>>>((const uint2*)y,z,adj,rp,bsum,sb+HD,mask,(u32*)xh,(u32*)xl,out,1);
}

// Round 3
// 303.041 us; speedup vs baseline: 1.3578x; 1.0182x over previous
//
#include <hip/hip_runtime.h>
#include <hip/hip_bf16.h>

#define NODES 32768
#define HD 128
#define NE 524288
#define NR 8

typedef unsigned int u32;
typedef unsigned short u16;
typedef __attribute__((ext_vector_type(8))) short bf16x8;
typedef __attribute__((ext_vector_type(4))) float f32x4;

// ---- ws byte offsets ----
#define XH_OFF   (0u)                      // bf16 hi, 8 MB
#define XL_OFF   (8u<<20)                  // bf16 lo, 8 MB
#define Y_OFF    (16u<<20)                 // bf16 y[8][NODES][128], 64 MB
#define Z_OFF    (80u<<20)                 // fp32 z[NODES][128], 16 MB
#define ADJ_OFF  (96u<<20)                 // u32 x NE (row ids)
#define RP_OFF   (98u<<20)                 // u32 x (NODES+1), block-local prefix
#define CUR_OFF  ((98u<<20)+(256u<<10))    // u32 x NODES
#define BSUM_OFF ((98u<<20)+(512u<<10))    // u32 x 129, block sums exclusive prefix
#define BP_OFF   ((98u<<20)+(640u<<10))    // packed weights bf16

#define BP_LAYER 294912                    // 9*2*16384
#define PP_ELEM  589824                    // pW packed at Bp+PP_ELEM (2 segs x 16384)

__device__ __forceinline__ float bflo(u32 u){ union{u32 i;float f;}c; c.i=u<<16; return c.f; }
__device__ __forceinline__ float bfhi(u32 u){ union{u32 i;float f;}c; c.i=u&0xffff0000u; return c.f; }
__device__ __forceinline__ u16 f2bf(float f){
  u32 u=__float_as_uint(f);
  u32 r=u + 0x7fffu + ((u>>16)&1u);
  return (u16)(r>>16);
}
__device__ __forceinline__ float bf2f(u16 h){ return __uint_as_float(((u32)h)<<16); }

__device__ __forceinline__ void gl_lds16(const void* g, void* l){
  __builtin_amdgcn_global_load_lds((const __attribute__((address_space(1))) u32*)g,
                                   (__attribute__((address_space(3))) u32*)l, 16, 0, 0);
}

// ---------------- weight prep: 2 layers x 9 tiles (8 rel + self) + pW, hi/lo segs ----
// MFMA-fragment-contiguous: k = ks*32 + q*8 + j -> (ks*128+n)*32 + q*8 + j
__global__ void prep_w(const float* __restrict__ rW, const float* __restrict__ sW,
                       const float* __restrict__ pWg, u16* __restrict__ Bp)
{
  int idx=blockIdx.x*256+threadIdx.x;           // 311296 total
  if(idx<294912){
    int l=idx/147456;
    int rem=idx%147456;
    int t=rem>>14;
    int kn=rem&16383;
    int k=kn>>7, n=kn&127;
    float w;
    if(t<8) w=rW[(((size_t)l*NR+t)*HD+n)*HD+k];
    else    w=sW[((size_t)l*HD+n)*HD+k];
    u16* base=Bp+(size_t)l*BP_LAYER+(size_t)t*32768;
    int ks=k>>5, q=(k>>3)&3, j=k&7;
    size_t off=((size_t)ks*128+n)*32+q*8+j;
    u16 hb=f2bf(w);
    u16 lb=f2bf(w-bf2f(hb));
    base[off]=hb;
    base[off+16384]=lb;
  } else {
    int kn=idx-294912;
    int k=kn>>7, n=kn&127;
    float w=pWg[(size_t)n*HD+k];
    u16* base=Bp+PP_ELEM;
    int ks=k>>5, q=(k>>3)&3, j=k&7;
    size_t off=((size_t)ks*128+n)*32+q*8+j;
    u16 hb=f2bf(w);
    u16 lb=f2bf(w-bf2f(hb));
    base[off]=hb;
    base[off+16384]=lb;
  }
}

// ---------------- embed_mfma: x = (cemb[cid]+kemb[kid]) @ pW^T + pb -> xh/xl ----------
__global__ __launch_bounds__(256,2) void embed_mfma(
    const int* __restrict__ cid, const int* __restrict__ kid,
    const float* __restrict__ cemb, const float* __restrict__ kemb,
    const u16* __restrict__ PP, const float* __restrict__ pb,
    u16* __restrict__ xh, u16* __restrict__ xl)
{
  __shared__ u16 Atile[2][128*128];   // [0]=hi [1]=lo, 64 KB, XOR-16 swizzle
  const int tid=threadIdx.x;
  const int wave=tid>>6, lane=tid&63;
  const int wm=wave>>1, wn=wave&1;
  const int q=lane>>4;
  const int d0=blockIdx.x*128;

  // ---- gather + add + split + LDS write: thread = (row=tid>>1, half=tid&1) ----
  { int r=tid>>1, half=tid&1;
    int ci=cid[d0+r], ki=kid[d0+r];
    const float* cp=cemb+(size_t)ci*HD+half*64;
    const float* kp=kemb+(size_t)ki*HD+half*64;
#pragma unroll
    for(int cc=0;cc<8;cc++){
      float4 a0=*(const float4*)(cp+cc*8);
      float4 a1=*(const float4*)(cp+cc*8+4);
      float4 b0=*(const float4*)(kp+cc*8);
      float4 b1=*(const float4*)(kp+cc*8+4);
      float v[8]={a0.x+b0.x,a0.y+b0.y,a0.z+b0.z,a0.w+b0.w,
                  a1.x+b1.x,a1.y+b1.y,a1.z+b1.z,a1.w+b1.w};
      u16 hb[8], lb[8];
#pragma unroll
      for(int j=0;j<8;j++){ hb[j]=f2bf(v[j]); lb[j]=f2bf(v[j]-bf2f(hb[j])); }
      int chunk=half*8+cc;
      int dst=r*128+(chunk^(r&15))*8;
      uint4 hv={(u32)hb[0]|((u32)hb[1]<<16),(u32)hb[2]|((u32)hb[3]<<16),
                (u32)hb[4]|((u32)hb[5]<<16),(u32)hb[6]|((u32)hb[7]<<16)};
      uint4 lv={(u32)lb[0]|((u32)lb[1]<<16),(u32)lb[2]|((u32)lb[3]<<16),
                (u32)lb[4]|((u32)lb[5]<<16),(u32)lb[6]|((u32)lb[7]<<16)};
      *(uint4*)&Atile[0][dst]=hv;
      *(uint4*)&Atile[1][dst]=lv;
    }
  }
  __syncthreads();

  f32x4 acc[4][4];
#pragma unroll
  for(int a=0;a<4;a++)
#pragma unroll
    for(int b=0;b<4;b++) acc[a][b]=(f32x4){0.f,0.f,0.f,0.f};

  // part 0: hi @ {Whi, Wlo}
#pragma unroll
  for(int ks=0;ks<4;ks++){
    bf16x8 ah[4];
#pragma unroll
    for(int tm=0;tm<4;tm++){
      int m=wm*64+tm*16+(lane&15);
      ah[tm]=*(const bf16x8*)&Atile[0][m*128+(((ks*4)+q)^(m&15))*8];
    }
#pragma unroll
    for(int s=0;s<2;s++){
      const u16* Bb=PP+s*16384;
#pragma unroll
      for(int tn=0;tn<4;tn++){
        int n=wn*64+tn*16+(lane&15);
        bf16x8 bfr=*(const bf16x8*)&Bb[((size_t)ks*128+n)*32+q*8];
#pragma unroll
        for(int tm=0;tm<4;tm++)
          acc[tm][tn]=__builtin_amdgcn_mfma_f32_16x16x32_bf16(ah[tm],bfr,acc[tm][tn],0,0,0);
      }
    }
  }
  // part 1: lo @ Whi
#pragma unroll
  for(int ks=0;ks<4;ks++){
    bf16x8 al[4];
#pragma unroll
    for(int tm=0;tm<4;tm++){
      int m=wm*64+tm*16+(lane&15);
      al[tm]=*(const bf16x8*)&Atile[1][m*128+(((ks*4)+q)^(m&15))*8];
    }
#pragma unroll
    for(int tn=0;tn<4;tn++){
      int n=wn*64+tn*16+(lane&15);
      bf16x8 bfr=*(const bf16x8*)&PP[((size_t)ks*128+n)*32+q*8];
#pragma unroll
      for(int tm=0;tm<4;tm++)
        acc[tm][tn]=__builtin_amdgcn_mfma_f32_16x16x32_bf16(al[tm],bfr,acc[tm][tn],0,0,0);
    }
  }

  // epilogue: +pb, split hi/lo; C/D layout col=lane&15, row=(lane>>4)*4+reg
#pragma unroll
  for(int tn=0;tn<4;tn++){
    int n=wn*64+tn*16+(lane&15);
    float b=pb[n];
#pragma unroll
    for(int tm=0;tm<4;tm++){
      int rbase=d0+wm*64+tm*16+q*4;
#pragma unroll
      for(int r=0;r<4;r++){
        float v=acc[tm][tn][r]+b;
        u16 hb=f2bf(v);
        u16 lb=f2bf(v-bf2f(hb));
        xh[(size_t)(rbase+r)*HD+n]=hb;
        xl[(size_t)(rbase+r)*HD+n]=lb;
      }
    }
  }
}

// ---------------- CSR build ----------------
__global__ void count_deg(const int* __restrict__ dst, u32* __restrict__ cnt){
  int e=blockIdx.x*256+threadIdx.x;
  atomicAdd(&cnt[dst[e]],1u);
}

__global__ void scan1(u32* __restrict__ cnt, u32* __restrict__ rp, u32* __restrict__ bsum){
  __shared__ u32 sh[256];
  int t=threadIdx.x; int base=blockIdx.x*256;
  u32 v=cnt[base+t]; sh[t]=v;
  cnt[base+t]=0u;                       // re-zero cur for scatter
  __syncthreads();
  for(int off=1;off<256;off<<=1){
    u32 tv=(t>=off)?sh[t-off]:0u; __syncthreads();
    sh[t]+=tv; __syncthreads();
  }
  rp[base+t]=sh[t]-v;
  if(t==255) bsum[blockIdx.x]=sh[255];
}

__global__ void scan2(u32* __restrict__ bsum, u32* __restrict__ rp){
  __shared__ u32 sh[128];
  int t=threadIdx.x;
  u32 v=bsum[t]; sh[t]=v; __syncthreads();
  for(int off=1;off<128;off<<=1){
    u32 tv=(t>=off)?sh[t-off]:0u; __syncthreads();
    sh[t]+=tv; __syncthreads();
  }
  bsum[t]=sh[t]-v;
  if(t==0){ rp[NODES]=NE; bsum[128]=0u; }
}

__global__ void scatter_edges(const int* __restrict__ src, const int* __restrict__ dst,
                              const int* __restrict__ et, const u32* __restrict__ rp,
                              const u32* __restrict__ bsum,
                              u32* __restrict__ cur, u32* __restrict__ adj){
  int e=blockIdx.x*256+threadIdx.x;
  int d=dst[e];
  u32 pos=atomicAdd(&cur[d],1u);
  adj[rp[d]+bsum[d>>8]+pos]=(u32)(et[e]*NODES+src[e]);   // precomputed y-row id
}

// ---------------- gemm_y: 64-row tile, ONE t per block, Whi-reuse, LDS-repack stores --
// y[t] = x @ W_t^T (t<8, bf16 out), z = x @ selfW^T (t==8, fp32 out)
// grid (NODES/64, 9). Inner loop loads each Whi fragment ONCE (used by hi and lo A):
// B loads 24 -> 16 per wave. Epilogue repacks the tile through LDS (reusing Atile)
// so global writes are full-line dwordx4 instead of scalar u16 (4x fewer requests).
__global__ __launch_bounds__(256,4) void gemm_y(
    const u16* __restrict__ xhi, const u16* __restrict__ xlo,
    const u16* __restrict__ Bt, u16* __restrict__ y, float* __restrict__ z)
{
  __shared__ u16 Atile[2][64*128];    // [0]=hi [1]=lo; row=256B, XOR-16 swizzle; 32 KB
  const int tid=threadIdx.x;
  const int wave=tid>>6, lane=tid&63;
  const int q=lane>>4;
  const int d0=blockIdx.x*64;
  const int t=blockIdx.y;
  const u16* Btile=Bt+(size_t)t*32768;

  const int st_c  = lane&15;
  const int st_rin= lane>>4;

#pragma unroll
  for(int i=0;i<4;i++){
    int rbase=wave*16+i*4;
    int r=rbase+st_rin;
    int g=st_c ^ (r&15);
    gl_lds16(xhi+(size_t)(d0+r)*HD+g*8, &Atile[0][rbase*128]);
  }
#pragma unroll
  for(int i=0;i<4;i++){
    int rbase=wave*16+i*4;
    int r=rbase+st_rin;
    int g=st_c ^ (r&15);
    gl_lds16(xlo+(size_t)(d0+r)*HD+g*8, &Atile[1][rbase*128]);
  }
  __syncthreads();

  f32x4 acc[4][2];
#pragma unroll
  for(int a=0;a<4;a++)
#pragma unroll
    for(int b=0;b<2;b++) acc[a][b]=(f32x4){0.f,0.f,0.f,0.f};

  // fused loop: per ks, load B hi/lo fragments once, A hi/lo frags, 12 MFMAs per tn.
#pragma unroll
  for(int ks=0;ks<4;ks++){
    bf16x8 bh[2], bl[2];
#pragma unroll
    for(int tn=0;tn<2;tn++){
      int n=wave*32+tn*16+(lane&15);
      size_t boff=((size_t)ks*128+n)*32+q*8;
      bh[tn]=*(const bf16x8*)&Btile[boff];
      bl[tn]=*(const bf16x8*)&Btile[boff+16384];
    }
    bf16x8 ah[4], al[4];
#pragma unroll
    for(int tm=0;tm<4;tm++){
      int m=tm*16+(lane&15);
      int aoff=m*128+(((ks*4)+q)^(m&15))*8;
      ah[tm]=*(const bf16x8*)&Atile[0][aoff];
      al[tm]=*(const bf16x8*)&Atile[1][aoff];
    }
#pragma unroll
    for(int tn=0;tn<2;tn++){
#pragma unroll
      for(int tm=0;tm<4;tm++)
        acc[tm][tn]=__builtin_amdgcn_mfma_f32_16x16x32_bf16(ah[tm],bh[tn],acc[tm][tn],0,0,0);
#pragma unroll
      for(int tm=0;tm<4;tm++)
        acc[tm][tn]=__builtin_amdgcn_mfma_f32_16x16x32_bf16(al[tm],bh[tn],acc[tm][tn],0,0,0);
#pragma unroll
      for(int tm=0;tm<4;tm++)
        acc[tm][tn]=__builtin_amdgcn_mfma_f32_16x16x32_bf16(ah[tm],bl[tn],acc[tm][tn],0,0,0);
    }
  }

  // ---- epilogue: repack through LDS (Atile is dead), then full-line dwordx4 stores ----
  __syncthreads();   // all waves done reading Atile
  if(t<8){
    // bf16 tile [64 rows][128 cols], row stride 256B in LDS; swizzle bits5-6 ^= (row>>2)&3
    u16* S=(u16*)Atile;
#pragma unroll
    for(int tn=0;tn<2;tn++){
      int col=wave*32+tn*16+(lane&15);
#pragma unroll
      for(int tm=0;tm<4;tm++){
#pragma unroll
        for(int r=0;r<4;r++){
          int row=tm*16+q*4+r;
          u32 ab=(u32)(row*256+col*2);
          ab^=((u32)((row>>2)&3))<<5;
          S[ab>>1]=f2bf(acc[tm][tn][r]);
        }
      }
    }
    __syncthreads();
    const char* Sb=(const char*)S;
    char* yb=(char*)(y+((size_t)t*NODES+d0)*HD);
#pragma unroll
    for(int i=0;i<4;i++){
      u32 byte=(u32)(i*256+tid)*16;          // 16KB tile, lanes 0-15 = one full 256B row
      u32 row=byte>>8;
      u32 lb=byte^(((row>>2)&3)<<5);
      uint4 v=*(const uint4*)(Sb+lb);
      *(uint4*)(yb+byte)=v;
    }
  } else {
    // fp32 tile [64 rows][128 cols], row stride 512B; swizzle bits6-7 ^= (row>>2)&3
    float* Sf=(float*)Atile;
#pragma unroll
    for(int tn=0;tn<2;tn++){
      int col=wave*32+tn*16+(lane&15);
#pragma unroll
      for(int tm=0;tm<4;tm++){
#pragma unroll
        for(int r=0;r<4;r++){
          int row=tm*16+q*4+r;
          u32 ab=(u32)(row*512+col*4);
          ab^=((u32)((row>>2)&3))<<6;
          Sf[ab>>2]=acc[tm][tn][r];
        }
      }
    }
    __syncthreads();
    const char* Sb=(const char*)Sf;
    char* zb=(char*)(z+(size_t)d0*HD);
#pragma unroll
    for(int i=0;i<8;i++){
      u32 byte=(u32)(i*256+tid)*16;          // 32KB tile
      u32 row=byte>>9;
      u32 lb=byte^(((row>>2)&3)<<6);
      uint4 v=*(const uint4*)(Sb+lb);
      *(uint4*)(zb+byte)=v;
    }
  }
}

// ---------------- gather_combine: agg = (1/deg) * sum_e y[row_e]; out = relu(z+agg+b)
__global__ __launch_bounds__(256) void gather_combine(
    const uint2* __restrict__ yy, const float* __restrict__ z,
    const u32* __restrict__ adj, const u32* __restrict__ rp, const u32* __restrict__ bsum,
    const float* __restrict__ sb, const int* __restrict__ mask,
    u32* __restrict__ xh, u32* __restrict__ xl, float* __restrict__ outf, int last)
{
  const int wave=threadIdx.x>>6, lane=threadIdx.x&63;
  const int node=blockIdx.x*4+wave;
  const int sub=lane>>5, c=lane&31;
  const int beg=(int)(rp[node]+bsum[node>>8]);
  const int end=(int)(rp[node+1]+bsum[(node+1)>>8]);
  float a0=0.f,a1=0.f,a2=0.f,a3=0.f;

  for(int base=beg; base<end; base+=64){
    int nk=end-base; if(nk>64) nk=64;
    u32 adjv = (lane<nk) ? adj[base+lane] : 0u;
    int i=0;
    for(; i+16<=nk; i+=16){
      uint2 vv[8];
#pragma unroll
      for(int j=0;j<8;j++){
        u32 row=(u32)__shfl((int)adjv, i+j*2+sub);
        vv[j]=yy[(size_t)row*32+c];
      }
#pragma unroll
      for(int j=0;j<8;j++){
        a0+=bflo(vv[j].x); a1+=bfhi(vv[j].x);
        a2+=bflo(vv[j].y); a3+=bfhi(vv[j].y);
      }
    }
    for(; i+2<=nk; i+=2){
      u32 row=(u32)__shfl((int)adjv, i+sub);
      uint2 v=yy[(size_t)row*32+c];
      a0+=bflo(v.x); a1+=bfhi(v.x); a2+=bflo(v.y); a3+=bfhi(v.y);
    }
    if(i<nk){
      u32 row=(u32)__shfl((int)adjv, i);
      if(sub==0){
        uint2 v=yy[(size_t)row*32+c];
        a0+=bflo(v.x); a1+=bfhi(v.x); a2+=bflo(v.y); a3+=bfhi(v.y);
      }
    }
  }

  a0+=__shfl_xor(a0,32); a1+=__shfl_xor(a1,32);
  a2+=__shfl_xor(a2,32); a3+=__shfl_xor(a3,32);

  if(sub==0){
    float inv=1.f/fmaxf((float)(end-beg),1.f);
    float4 zz=*(const float4*)&z[(size_t)node*HD+c*4];
    float4 bb=*(const float4*)&sb[c*4];
    float v0=fmaxf(zz.x+a0*inv+bb.x,0.f);
    float v1=fmaxf(zz.y+a1*inv+bb.y,0.f);
    float v2=fmaxf(zz.z+a2*inv+bb.z,0.f);
    float v3=fmaxf(zz.w+a3*inv+bb.w,0.f);
    if(last){
      float mk=(float)mask[node];
      float4 o={v0*mk,v1*mk,v2*mk,v3*mk};
      *(float4*)&outf[(size_t)node*HD+c*4]=o;
    } else {
      u16 h0=f2bf(v0), h1=f2bf(v1), h2=f2bf(v2), h3=f2bf(v3);
      u16 l0=f2bf(v0-bf2f(h0)), l1=f2bf(v1-bf2f(h1));
      u16 l2=f2bf(v2-bf2f(h2)), l3=f2bf(v3-bf2f(h3));
      uint2 hv={(u32)h0|((u32)h1<<16),(u32)h2|((u32)h3<<16)};
      uint2 lv={(u32)l0|((u32)l1<<16),(u32)l2|((u32)l3<<16)};
      *(uint2*)&xh[(size_t)node*64+c*2]=hv;
      *(uint2*)&xl[(size_t)node*64+c*2]=lv;
    }
  }
}

extern "C" void kernel_launch(void* const* d_in, const int* in_sizes, int n_in,
                              void* d_out, int out_size, void* d_ws, size_t ws_size,
                              hipStream_t stream)
{
  (void)in_sizes; (void)n_in; (void)out_size; (void)ws_size;
  const int*   cid =(const int*)  d_in[0];
  const int*   kid =(const int*)  d_in[1];
  const int*   mask=(const int*)  d_in[2];
  const int*   ei  =(const int*)  d_in[3];
  const int*   et  =(const int*)  d_in[4];
  const float* cemb=(const float*)d_in[5];
  const float* kemb=(const float*)d_in[6];
  const float* pW  =(const float*)d_in[7];
  const float* pb  =(const float*)d_in[8];
  const float* sW  =(const float*)d_in[9];
  const float* sb  =(const float*)d_in[10];
  const float* rW  =(const float*)d_in[11];
  float* out=(float*)d_out;
  char*  ws =(char*)d_ws;

  u16* xh =(u16*)(ws+XH_OFF);
  u16* xl =(u16*)(ws+XL_OFF);
  u16* y  =(u16*)(ws+Y_OFF);
  float* z=(float*)(ws+Z_OFF);
  u32* adj =(u32*)(ws+ADJ_OFF);
  u32* rp  =(u32*)(ws+RP_OFF);
  u32* cur =(u32*)(ws+CUR_OFF);
  u32* bsum=(u32*)(ws+BSUM_OFF);
  u16* Bp  =(u16*)(ws+BP_OFF);
  const int* srcA=ei;
  const int* dstA=ei+NE;

  hipMemsetAsync(cur,0,NODES*sizeof(u32),stream);
  prep_w<<<1216,256,0,stream>>>(rW,sW,pW,Bp);
  embed_mfma<<<NODES/128,256,0,stream>>>(cid,kid,cemb,kemb,Bp+PP_ELEM,pb,xh,xl);
  count_deg<<<NE/256,256,0,stream>>>(dstA,cur);
  scan1<<<NODES/256,256,0,stream>>>(cur,rp,bsum);
  scan2<<<1,128,0,stream>>>(bsum,rp);
  scatter_edges<<<NE/256,256,0,stream>>>(srcA,dstA,et,rp,bsum,cur,adj);

  // layer 0
  gemm_y<<<dim3(NODES/64,9),256,0,stream>>>(xh,xl,Bp,y,z);
  gather_combine<<<NODES/4,256,0,stream>>>((const uint2*)y,z,adj,rp,bsum,sb,mask,(u32*)xh,(u32*)xl,out,0);
  // layer 1
  gemm_y<<<dim3(NODES/64,9),256,0,stream>>>(xh,xl,Bp+BP_LAYER,y,z);
  gather_combine<<<NODES/4,256,0,stream>>>((const uint2*)y,z,adj,rp,bsum,sb+HD,mask,(u32*)xh,(u32*)xl,out,1);
}